// Round 1
// baseline (823.936 us; speedup 1.0000x reference)
//
#include <hip/hip_runtime.h>
#include <math.h>

// Problem constants (B=2, S=2048 -> T=4096 tokens)
#define T_TOK 4096
#define HDIM  1024
#define FDIM  4096
#define NEXP  8
#define SLOT_CAP 9216   // 8192 pairs + 8 experts * 128 alignment pad

typedef __bf16 bf16x8 __attribute__((ext_vector_type(8)));
typedef __bf16 bf16x4 __attribute__((ext_vector_type(4)));
typedef float  f32x4  __attribute__((ext_vector_type(4)));

__device__ __forceinline__ void gload_lds16(const void* g, void* l) {
  __builtin_amdgcn_global_load_lds((const __attribute__((address_space(1))) void*)g,
                                   (__attribute__((address_space(3))) void*)l,
                                   16, 0, 0);
}

// ---------------- router: scores, top-2, bf16 cast of x ----------------
__global__ void router_k(const float* __restrict__ x, const float* __restrict__ rw,
                         __bf16* __restrict__ xb, int* __restrict__ cnt,
                         int* __restrict__ tok_e, int* __restrict__ tok_pos,
                         float* __restrict__ tok_gate) {
  const int wv   = threadIdx.x >> 6;
  const int lane = threadIdx.x & 63;
  const int t = blockIdx.x * 4 + wv;
  const float* xr = x + (size_t)t * HDIM;
  __bf16* xbr = xb + (size_t)t * HDIM;
  float acc[8];
#pragma unroll
  for (int e = 0; e < 8; ++e) acc[e] = 0.0f;
#pragma unroll
  for (int i = 0; i < 16; ++i) {
    int h = lane + (i << 6);
    float xv = xr[h];
    xbr[h] = (__bf16)xv;
    const float4* rp = (const float4*)(rw + h * 8);
    float4 r0 = rp[0], r1 = rp[1];
    acc[0] += xv * r0.x; acc[1] += xv * r0.y; acc[2] += xv * r0.z; acc[3] += xv * r0.w;
    acc[4] += xv * r1.x; acc[5] += xv * r1.y; acc[6] += xv * r1.z; acc[7] += xv * r1.w;
  }
#pragma unroll
  for (int s = 32; s >= 1; s >>= 1) {
#pragma unroll
    for (int e = 0; e < 8; ++e) acc[e] += __shfl_xor(acc[e], s, 64);
  }
  if (lane == 0) {
    float v0 = acc[0]; int b0 = 0;
#pragma unroll
    for (int e = 1; e < 8; ++e) { if (acc[e] > v0) { v0 = acc[e]; b0 = e; } }
    float v1 = -1e30f; int b1i = 0;
#pragma unroll
    for (int e = 0; e < 8; ++e) { if (e != b0 && acc[e] > v1) { v1 = acc[e]; b1i = e; } }
    float g0 = 1.0f / (1.0f + expf(-v0));
    float g1 = 1.0f / (1.0f + expf(-v1));
    int p0 = atomicAdd(&cnt[b0], 1);
    int p1 = atomicAdd(&cnt[b1i], 1);
    tok_e[t * 2] = b0;    tok_e[t * 2 + 1] = b1i;
    tok_pos[t * 2] = p0;  tok_pos[t * 2 + 1] = p1;
    tok_gate[t * 2] = g0; tok_gate[t * 2 + 1] = g1;
  }
}

// ---------------- prefix offsets (128-aligned per expert) ----------------
__global__ void offs_k(const int* __restrict__ cnt, int* __restrict__ offs) {
  if (threadIdx.x == 0) {
    int r = 0;
    for (int e = 0; e < NEXP; ++e) { offs[e] = r; r += (cnt[e] + 127) & ~127; }
  }
}

// ---------------- scatter pairs into slot order ----------------
__global__ void build_k(const int* __restrict__ tok_e, const int* __restrict__ tok_pos,
                        const float* __restrict__ tok_gate, const int* __restrict__ offs,
                        int* __restrict__ slot_tok, float* __restrict__ slot_gate) {
  int idx = blockIdx.x * blockDim.x + threadIdx.x;   // 0..8191
  int e = tok_e[idx];
  int slot = offs[e] + tok_pos[idx];
  slot_tok[slot] = idx >> 1;
  slot_gate[slot] = tok_gate[idx];
}

// ---------------- fp32 -> bf16 transposed weight copy ----------------
// in: [E][R][C] fp32, out: [E][C][R] bf16. grid (C/64, R/64, E), block 256.
__global__ void transpose_cvt(const float* __restrict__ in, __bf16* __restrict__ outp,
                              int R, int C) {
  __shared__ float tile[64][65];
  const int e = blockIdx.z;
  const int c0 = blockIdx.x * 64;
  const int r0 = blockIdx.y * 64;
  const int tr = threadIdx.x >> 4;          // 0..15
  const int tc4 = (threadIdx.x & 15) * 4;   // 0..60
  const float* ibase = in + (size_t)e * R * C;
#pragma unroll
  for (int i = 0; i < 4; ++i) {
    int r = r0 + tr + i * 16;
    float4 v = *(const float4*)(ibase + (size_t)r * C + c0 + tc4);
    tile[tr + i * 16][tc4 + 0] = v.x;
    tile[tr + i * 16][tc4 + 1] = v.y;
    tile[tr + i * 16][tc4 + 2] = v.z;
    tile[tr + i * 16][tc4 + 3] = v.w;
  }
  __syncthreads();
  __bf16* obase = outp + (size_t)e * R * C;
#pragma unroll
  for (int i = 0; i < 4; ++i) {
    int c = c0 + tr + i * 16;
    bf16x4 o;
#pragma unroll
    for (int j = 0; j < 4; ++j) o[j] = (__bf16)tile[tc4 + j][tr + i * 16];
    *(bf16x4*)(obase + (size_t)c * R + r0 + tc4) = o;
  }
}

// ---------------- grouped GEMM, m97-style 128x128xBK64 ----------------
// G1: A = xb gathered by slot_tok, epilogue = gelu(acc+b1) -> hbuf (bf16)
// !G1: A = hbuf rows, epilogue = atomicAdd(out[tok][n], gate*(acc+b2))
template<bool G1>
__global__ __launch_bounds__(256) void moe_gemm(
    const __bf16* __restrict__ A, const __bf16* __restrict__ B,
    const float* __restrict__ bias,
    __bf16* __restrict__ hout, float* __restrict__ out,
    const int* __restrict__ cnt, const int* __restrict__ offs,
    const int* __restrict__ slot_tok, const float* __restrict__ slot_gate,
    int N, int K)
{
  const int e = blockIdx.z;
  const int cnt_e = cnt[e];
  const int mtile = blockIdx.y;
  if (mtile * 128 >= cnt_e) return;
  const int offs_e = offs[e];
  const int nbase = blockIdx.x * 128;

  __shared__ __bf16 As[128 * 64];
  __shared__ __bf16 Bs[128 * 64];

  const int tid = threadIdx.x;
  const int w = tid >> 6, lane = tid & 63;
  const int wy = w >> 1, wx = w & 1;
  const int lm = lane & 15, quad = lane >> 4;
  const int srow = lane >> 3;     // 0..7
  const int scol = lane & 7;      // 0..7, x8 elements

  const __bf16* aptr[4];
  const __bf16* bptr[4];
#pragma unroll
  for (int it = 0; it < 4; ++it) {
    int rl = w * 32 + it * 8 + srow;        // tile row 0..127
    long arow;
    if constexpr (G1) {
      int gm = mtile * 128 + rl;
      int tok = (gm < cnt_e) ? slot_tok[offs_e + gm] : 0;
      arow = (long)tok;
    } else {
      arow = (long)(offs_e + mtile * 128 + rl);
    }
    aptr[it] = A + arow * (long)K + scol * 8;
    bptr[it] = B + ((long)e * N + nbase + rl) * (long)K + scol * 8;
  }

  f32x4 acc[4][4];
#pragma unroll
  for (int mt = 0; mt < 4; ++mt)
#pragma unroll
    for (int nt = 0; nt < 4; ++nt) acc[mt][nt] = (f32x4){0.f, 0.f, 0.f, 0.f};

  const int ksteps = K >> 6;
  for (int ks = 0; ks < ksteps; ++ks) {
    const int kofs = ks * 64;
#pragma unroll
    for (int it = 0; it < 4; ++it)
      gload_lds16(aptr[it] + kofs, &As[(w * 32 + it * 8) * 64]);
#pragma unroll
    for (int it = 0; it < 4; ++it)
      gload_lds16(bptr[it] + kofs, &Bs[(w * 32 + it * 8) * 64]);
    __syncthreads();

    const bf16x8* Af = reinterpret_cast<const bf16x8*>(As);
    const bf16x8* Bf = reinterpret_cast<const bf16x8*>(Bs);
#pragma unroll
    for (int kf = 0; kf < 2; ++kf) {
      bf16x8 a[4], b[4];
#pragma unroll
      for (int mt = 0; mt < 4; ++mt)
        a[mt] = Af[(wy * 64 + mt * 16 + lm) * 8 + kf * 4 + quad];
#pragma unroll
      for (int nt = 0; nt < 4; ++nt)
        b[nt] = Bf[(wx * 64 + nt * 16 + lm) * 8 + kf * 4 + quad];
#pragma unroll
      for (int mt = 0; mt < 4; ++mt)
#pragma unroll
        for (int nt = 0; nt < 4; ++nt)
          acc[mt][nt] = __builtin_amdgcn_mfma_f32_16x16x32_bf16(a[mt], b[nt], acc[mt][nt], 0, 0, 0);
    }
    __syncthreads();
  }

  if constexpr (G1) {
#pragma unroll
    for (int nt = 0; nt < 4; ++nt) {
      int n = nbase + wx * 64 + nt * 16 + lm;
      float bv = bias[e * N + n];
#pragma unroll
      for (int mt = 0; mt < 4; ++mt) {
        int mrow = wy * 64 + mt * 16 + quad * 4;
        f32x4 c = acc[mt][nt];
#pragma unroll
        for (int i = 0; i < 4; ++i) {
          int gm = mtile * 128 + mrow + i;
          if (gm < cnt_e) {
            float v = c[i] + bv;
            v = 0.5f * v * (1.0f + erff(v * 0.70710678118654752f));
            hout[(size_t)(offs_e + gm) * FDIM + n] = (__bf16)v;
          }
        }
      }
    }
  } else {
    float bv[4]; int nn[4];
#pragma unroll
    for (int nt = 0; nt < 4; ++nt) {
      nn[nt] = nbase + wx * 64 + nt * 16 + lm;
      bv[nt] = bias[e * N + nn[nt]];
    }
#pragma unroll
    for (int mt = 0; mt < 4; ++mt) {
      int mrow = wy * 64 + mt * 16 + quad * 4;
#pragma unroll
      for (int i = 0; i < 4; ++i) {
        int gm = mtile * 128 + mrow + i;
        if (gm >= cnt_e) continue;
        int slot = offs_e + gm;
        int t = slot_tok[slot];
        float g = slot_gate[slot];
        float* orow = out + (size_t)t * HDIM;
#pragma unroll
        for (int nt = 0; nt < 4; ++nt) {
          float v = acc[mt][nt][i] + bv[nt];
          atomicAdd(&orow[nn[nt]], g * v);
        }
      }
    }
  }
}

__global__ void ws_too_small_k(float* out, float v) {
  if (threadIdx.x == 0 && blockIdx.x == 0) out[0] = v;
}

extern "C" void kernel_launch(void* const* d_in, const int* in_sizes, int n_in,
                              void* d_out, int out_size, void* d_ws, size_t ws_size,
                              hipStream_t stream) {
  const float* x  = (const float*)d_in[0];   // [2,2048,1024]
  const float* rw = (const float*)d_in[1];   // [1024,8]
  const float* w1 = (const float*)d_in[2];   // [8,1024,4096]
  const float* b1 = (const float*)d_in[3];   // [8,4096]
  const float* w2 = (const float*)d_in[4];   // [8,4096,1024]
  const float* b2 = (const float*)d_in[5];   // [8,1024]
  float* out = (float*)d_out;
  char* ws = (char*)d_ws;

  // workspace layout
  size_t o = 0;
  size_t o_xb = o;        o += (size_t)T_TOK * HDIM * 2;            // bf16 x
  size_t o_w1t = o;       o += (size_t)NEXP * FDIM * HDIM * 2;      // bf16 [E][F][H]
  size_t o_w2t = o;       o += (size_t)NEXP * HDIM * FDIM * 2;      // bf16 [E][H][F]
  size_t o_hbuf = o;      o += (size_t)SLOT_CAP * FDIM * 2;         // bf16 gelu acts
  size_t o_slot_tok = o;  o += (size_t)SLOT_CAP * 4;
  size_t o_slot_gate = o; o += (size_t)SLOT_CAP * 4;
  size_t o_tok_e = o;     o += (size_t)T_TOK * 2 * 4;
  size_t o_tok_pos = o;   o += (size_t)T_TOK * 2 * 4;
  size_t o_tok_gate = o;  o += (size_t)T_TOK * 2 * 4;
  size_t o_cnt = o;       o += 64;
  size_t o_offs = o;      o += 64;
  const size_t NEED = o;

  hipMemsetAsync(d_out, 0, (size_t)out_size * 4, stream);
  if (ws_size < NEED) {
    // signal available ws_size through the absmax error so we can diagnose
    ws_too_small_k<<<1, 64, 0, stream>>>(out, (float)ws_size);
    return;
  }

  __bf16* xb   = (__bf16*)(ws + o_xb);
  __bf16* w1t  = (__bf16*)(ws + o_w1t);
  __bf16* w2t  = (__bf16*)(ws + o_w2t);
  __bf16* hbuf = (__bf16*)(ws + o_hbuf);
  int*   slot_tok  = (int*)(ws + o_slot_tok);
  float* slot_gate = (float*)(ws + o_slot_gate);
  int*   tok_e    = (int*)(ws + o_tok_e);
  int*   tok_pos  = (int*)(ws + o_tok_pos);
  float* tok_gate = (float*)(ws + o_tok_gate);
  int*   cnt  = (int*)(ws + o_cnt);
  int*   offs = (int*)(ws + o_offs);

  hipMemsetAsync(cnt, 0, 64, stream);

  // weight transposes (independent of router)
  transpose_cvt<<<dim3(FDIM / 64, HDIM / 64, NEXP), 256, 0, stream>>>(w1, w1t, HDIM, FDIM);
  transpose_cvt<<<dim3(HDIM / 64, FDIM / 64, NEXP), 256, 0, stream>>>(w2, w2t, FDIM, HDIM);

  router_k<<<T_TOK / 4, 256, 0, stream>>>(x, rw, xb, cnt, tok_e, tok_pos, tok_gate);
  offs_k<<<1, 64, 0, stream>>>(cnt, offs);
  build_k<<<T_TOK * 2 / 256, 256, 0, stream>>>(tok_e, tok_pos, tok_gate, offs, slot_tok, slot_gate);

  // GEMM1: [cnt_e,1024] x [1024,4096] -> gelu -> hbuf
  moe_gemm<true><<<dim3(FDIM / 128, 32, NEXP), 256, 0, stream>>>(
      xb, w1t, b1, hbuf, nullptr, cnt, offs, slot_tok, slot_gate, FDIM, HDIM);
  // GEMM2: [cnt_e,4096] x [4096,1024] -> gate*( +b2) -> atomic out
  moe_gemm<false><<<dim3(HDIM / 128, 32, NEXP), 256, 0, stream>>>(
      hbuf, w2t, b2, nullptr, out, cnt, offs, slot_tok, slot_gate, HDIM, FDIM);
}

// Round 2
// 690.885 us; speedup vs baseline: 1.1926x; 1.1926x over previous
//
#include <hip/hip_runtime.h>
#include <math.h>

// Problem constants (B=2, S=2048 -> T=4096 tokens)
#define T_TOK 4096
#define HDIM  1024
#define FDIM  4096
#define NEXP  8
#define SLOT_CAP 9216   // 8192 pairs + 8 experts * 128 alignment pad
#define MAXTILES 72

typedef __bf16 bf16x8 __attribute__((ext_vector_type(8)));
typedef float  f32x4  __attribute__((ext_vector_type(4)));

__device__ __forceinline__ void gload_lds16(const void* g, void* l) {
  __builtin_amdgcn_global_load_lds((const __attribute__((address_space(1))) void*)g,
                                   (__attribute__((address_space(3))) void*)l,
                                   16, 0, 0);
}

// ---------------- router: scores, top-2, bf16 cast of x ----------------
__global__ void router_k(const float* __restrict__ x, const float* __restrict__ rw,
                         __bf16* __restrict__ xb, int* __restrict__ cnt,
                         int* __restrict__ tok_e, int* __restrict__ tok_pos,
                         float* __restrict__ tok_gate) {
  const int wv   = threadIdx.x >> 6;
  const int lane = threadIdx.x & 63;
  const int t = blockIdx.x * 4 + wv;
  const float* xr = x + (size_t)t * HDIM;
  __bf16* xbr = xb + (size_t)t * HDIM;
  float acc[8];
#pragma unroll
  for (int e = 0; e < 8; ++e) acc[e] = 0.0f;
#pragma unroll
  for (int i = 0; i < 16; ++i) {
    int h = lane + (i << 6);
    float xv = xr[h];
    xbr[h] = (__bf16)xv;
    const float4* rp = (const float4*)(rw + h * 8);
    float4 r0 = rp[0], r1 = rp[1];
    acc[0] += xv * r0.x; acc[1] += xv * r0.y; acc[2] += xv * r0.z; acc[3] += xv * r0.w;
    acc[4] += xv * r1.x; acc[5] += xv * r1.y; acc[6] += xv * r1.z; acc[7] += xv * r1.w;
  }
#pragma unroll
  for (int s = 32; s >= 1; s >>= 1) {
#pragma unroll
    for (int e = 0; e < 8; ++e) acc[e] += __shfl_xor(acc[e], s, 64);
  }
  if (lane == 0) {
    float v0 = acc[0]; int b0 = 0;
#pragma unroll
    for (int e = 1; e < 8; ++e) { if (acc[e] > v0) { v0 = acc[e]; b0 = e; } }
    float v1 = -1e30f; int b1i = 0;
#pragma unroll
    for (int e = 0; e < 8; ++e) { if (e != b0 && acc[e] > v1) { v1 = acc[e]; b1i = e; } }
    float g0 = 1.0f / (1.0f + expf(-v0));
    float g1 = 1.0f / (1.0f + expf(-v1));
    int p0 = atomicAdd(&cnt[b0], 1);
    int p1 = atomicAdd(&cnt[b1i], 1);
    tok_e[t * 2] = b0;    tok_e[t * 2 + 1] = b1i;
    tok_pos[t * 2] = p0;  tok_pos[t * 2 + 1] = p1;
    tok_gate[t * 2] = g0; tok_gate[t * 2 + 1] = g1;
  }
}

// ------- prefix offsets (128-aligned per expert) + flattened tile list -------
__global__ void offs_k(const int* __restrict__ cnt, int* __restrict__ offs,
                       int* __restrict__ tile_e, int* __restrict__ tile_m) {
  if (threadIdx.x == 0) {
    int r = 0, t = 0;
    for (int e = 0; e < NEXP; ++e) {
      offs[e] = r;
      int nt = (cnt[e] + 127) >> 7;
      for (int m = 0; m < nt; ++m) { tile_e[t] = e; tile_m[t] = m; ++t; }
      r += nt << 7;
    }
    for (; t < MAXTILES; ++t) { tile_e[t] = 0; tile_m[t] = 1 << 20; }
  }
}

// ---------------- scatter pairs into slot order ----------------
__global__ void build_k(const int* __restrict__ tok_e, const int* __restrict__ tok_pos,
                        const float* __restrict__ tok_gate, const int* __restrict__ offs,
                        int* __restrict__ slot_tok, float* __restrict__ slot_gate) {
  int idx = blockIdx.x * blockDim.x + threadIdx.x;   // 0..8191
  int e = tok_e[idx];
  int slot = offs[e] + tok_pos[idx];
  slot_tok[slot] = idx >> 1;
  slot_gate[slot] = tok_gate[idx];
}

// ------------- fp32 -> bf16 transposed weight copy (pair-pack) -------------
// in: [E][R][C] fp32, out: [E][C][R] bf16.
// Tile: 128 rows x 32 cols. grid (C/32, R/128, E), block 256.
// fp32->bf16 convert happens BEFORE LDS; row-pairs packed as bf16x2 (uint)
// so phase-2 reads are ds_read_b128 and global stores are 128B-contiguous.
__global__ __launch_bounds__(256) void transpose_cvt2(const float* __restrict__ in,
                                                      __bf16* __restrict__ outp,
                                                      int R, int C) {
  __shared__ unsigned int pt[32][68];   // [c][pair], pad 4 keeps 16B align + bank rotate
  const int e = blockIdx.z;
  const int c0 = blockIdx.x * 32;
  const int r0 = blockIdx.y * 128;
  const int tid = threadIdx.x;
  const float* ibase = in + (size_t)e * R * C + (size_t)r0 * C + c0;
  const int rp = tid >> 3;          // 0..31  (pair index low)
  const int cq = (tid & 7) * 4;     // 0..28  (col group)
#pragma unroll
  for (int i = 0; i < 2; ++i) {
    int p = rp + 32 * i;            // pair 0..63 -> rows 2p, 2p+1
    const float4 v0 = *(const float4*)(ibase + (size_t)(2 * p) * C + cq);
    const float4 v1 = *(const float4*)(ibase + (size_t)(2 * p + 1) * C + cq);
    union { __bf16 h[2]; unsigned int u; } pk;
    pk.h[0] = (__bf16)v0.x; pk.h[1] = (__bf16)v1.x; pt[cq + 0][p] = pk.u;
    pk.h[0] = (__bf16)v0.y; pk.h[1] = (__bf16)v1.y; pt[cq + 1][p] = pk.u;
    pk.h[0] = (__bf16)v0.z; pk.h[1] = (__bf16)v1.z; pt[cq + 2][p] = pk.u;
    pk.h[0] = (__bf16)v0.w; pk.h[1] = (__bf16)v1.w; pt[cq + 3][p] = pk.u;
  }
  __syncthreads();
  const int rs = tid & 7;           // pair-chunk low (4 pairs = 8 rows per b128)
  const int cc = tid >> 3;          // 0..31
  __bf16* obase = outp + (size_t)e * R * C + (size_t)c0 * R + r0;
#pragma unroll
  for (int i = 0; i < 2; ++i) {
    int ch = rs + 8 * i;            // chunk 0..15
    uint4 v = *(const uint4*)&pt[cc][ch * 4];
    *(uint4*)(obase + (size_t)cc * R + ch * 8) = v;
  }
}

// ---------------- grouped GEMM, 128x128xBK64, XOR-swizzled LDS ----------------
// LDS layout: logical (row, unit c in 0..7 of 8 bf16) stored at physical unit
// c ^ (row&7). global_load_lds writes lane (srow,scol) at phys unit scol, so the
// lane's GLOBAL source column is (scol^srow)*8 — same bytes land swizzled.
// G1: A = xb gathered by slot_tok, epilogue = gelu(acc+b1) -> hbuf (bf16)
// !G1: A = hbuf rows, epilogue = atomicAdd(out[tok][n], gate*(acc+b2))
template<bool G1>
__global__ __launch_bounds__(256) void moe_gemm(
    const __bf16* __restrict__ A, const __bf16* __restrict__ B,
    const float* __restrict__ bias,
    __bf16* __restrict__ hout, float* __restrict__ out,
    const int* __restrict__ cnt, const int* __restrict__ offs,
    const int* __restrict__ slot_tok, const float* __restrict__ slot_gate,
    const int* __restrict__ tile_e, const int* __restrict__ tile_m,
    int N, int K)
{
  const int e = tile_e[blockIdx.y];
  const int mtile = tile_m[blockIdx.y];
  const int cnt_e = cnt[e];
  if (mtile * 128 >= cnt_e) return;
  const int offs_e = offs[e];
  const int nbase = blockIdx.x * 128;

  __shared__ __bf16 As[128 * 64];
  __shared__ __bf16 Bs[128 * 64];

  const int tid = threadIdx.x;
  const int w = tid >> 6, lane = tid & 63;
  const int wy = w >> 1, wx = w & 1;
  const int lm = lane & 15, quad = lane >> 4;
  const int lm7 = lane & 7;
  const int srow = lane >> 3;     // 0..7
  const int scol = lane & 7;      // 0..7, x8 elements

  const __bf16* aptr[4];
  const __bf16* bptr[4];
#pragma unroll
  for (int it = 0; it < 4; ++it) {
    int rl = w * 32 + it * 8 + srow;        // tile row 0..127
    long arow;
    if constexpr (G1) {
      int gm = mtile * 128 + rl;
      int tok = (gm < cnt_e) ? slot_tok[offs_e + gm] : 0;
      arow = (long)tok;
    } else {
      arow = (long)(offs_e + mtile * 128 + rl);
    }
    const int swcol = (scol ^ srow) << 3;   // swizzled source column
    aptr[it] = A + arow * (long)K + swcol;
    bptr[it] = B + ((long)e * N + nbase + rl) * (long)K + swcol;
  }

  f32x4 acc[4][4];
#pragma unroll
  for (int mt = 0; mt < 4; ++mt)
#pragma unroll
    for (int nt = 0; nt < 4; ++nt) acc[mt][nt] = (f32x4){0.f, 0.f, 0.f, 0.f};

  const int ksteps = K >> 6;
  for (int ks = 0; ks < ksteps; ++ks) {
    const int kofs = ks * 64;
#pragma unroll
    for (int it = 0; it < 4; ++it)
      gload_lds16(aptr[it] + kofs, &As[(w * 32 + it * 8) * 64]);
#pragma unroll
    for (int it = 0; it < 4; ++it)
      gload_lds16(bptr[it] + kofs, &Bs[(w * 32 + it * 8) * 64]);
    __syncthreads();

    const bf16x8* Af = reinterpret_cast<const bf16x8*>(As);
    const bf16x8* Bf = reinterpret_cast<const bf16x8*>(Bs);
#pragma unroll
    for (int kf = 0; kf < 2; ++kf) {
      bf16x8 a[4], b[4];
#pragma unroll
      for (int mt = 0; mt < 4; ++mt)
        a[mt] = Af[(wy * 64 + mt * 16 + lm) * 8 + (((kf << 2) + quad) ^ lm7)];
#pragma unroll
      for (int nt = 0; nt < 4; ++nt)
        b[nt] = Bf[(wx * 64 + nt * 16 + lm) * 8 + (((kf << 2) + quad) ^ lm7)];
#pragma unroll
      for (int mt = 0; mt < 4; ++mt)
#pragma unroll
        for (int nt = 0; nt < 4; ++nt)
          acc[mt][nt] = __builtin_amdgcn_mfma_f32_16x16x32_bf16(a[mt], b[nt], acc[mt][nt], 0, 0, 0);
    }
    __syncthreads();
  }

  if constexpr (G1) {
#pragma unroll
    for (int nt = 0; nt < 4; ++nt) {
      int n = nbase + wx * 64 + nt * 16 + lm;
      float bv = bias[e * N + n];
#pragma unroll
      for (int mt = 0; mt < 4; ++mt) {
        int mrow = wy * 64 + mt * 16 + quad * 4;
        f32x4 c = acc[mt][nt];
#pragma unroll
        for (int i = 0; i < 4; ++i) {
          int gm = mtile * 128 + mrow + i;
          if (gm < cnt_e) {
            float v = c[i] + bv;
            v = 0.5f * v * (1.0f + erff(v * 0.70710678118654752f));
            hout[(size_t)(offs_e + gm) * FDIM + n] = (__bf16)v;
          }
        }
      }
    }
  } else {
    float bv[4]; int nn[4];
#pragma unroll
    for (int nt = 0; nt < 4; ++nt) {
      nn[nt] = nbase + wx * 64 + nt * 16 + lm;
      bv[nt] = bias[e * N + nn[nt]];
    }
#pragma unroll
    for (int mt = 0; mt < 4; ++mt) {
      int mrow = wy * 64 + mt * 16 + quad * 4;
#pragma unroll
      for (int i = 0; i < 4; ++i) {
        int gm = mtile * 128 + mrow + i;
        if (gm >= cnt_e) continue;
        int slot = offs_e + gm;
        int t = slot_tok[slot];
        float g = slot_gate[slot];
        float* orow = out + (size_t)t * HDIM;
#pragma unroll
        for (int nt = 0; nt < 4; ++nt) {
          float v = acc[mt][nt][i] + bv[nt];
          atomicAdd(&orow[nn[nt]], g * v);
        }
      }
    }
  }
}

__global__ void ws_too_small_k(float* out, float v) {
  if (threadIdx.x == 0 && blockIdx.x == 0) out[0] = v;
}

extern "C" void kernel_launch(void* const* d_in, const int* in_sizes, int n_in,
                              void* d_out, int out_size, void* d_ws, size_t ws_size,
                              hipStream_t stream) {
  const float* x  = (const float*)d_in[0];   // [2,2048,1024]
  const float* rw = (const float*)d_in[1];   // [1024,8]
  const float* w1 = (const float*)d_in[2];   // [8,1024,4096]
  const float* b1 = (const float*)d_in[3];   // [8,4096]
  const float* w2 = (const float*)d_in[4];   // [8,4096,1024]
  const float* b2 = (const float*)d_in[5];   // [8,1024]
  float* out = (float*)d_out;
  char* ws = (char*)d_ws;

  // workspace layout
  size_t o = 0;
  size_t o_xb = o;        o += (size_t)T_TOK * HDIM * 2;            // bf16 x
  size_t o_w1t = o;       o += (size_t)NEXP * FDIM * HDIM * 2;      // bf16 [E][F][H]
  size_t o_w2t = o;       o += (size_t)NEXP * HDIM * FDIM * 2;      // bf16 [E][H][F]
  size_t o_hbuf = o;      o += (size_t)SLOT_CAP * FDIM * 2;         // bf16 gelu acts
  size_t o_slot_tok = o;  o += (size_t)SLOT_CAP * 4;
  size_t o_slot_gate = o; o += (size_t)SLOT_CAP * 4;
  size_t o_tok_e = o;     o += (size_t)T_TOK * 2 * 4;
  size_t o_tok_pos = o;   o += (size_t)T_TOK * 2 * 4;
  size_t o_tok_gate = o;  o += (size_t)T_TOK * 2 * 4;
  size_t o_cnt = o;       o += 64;
  size_t o_offs = o;      o += 64;
  size_t o_tile = o;      o += MAXTILES * 2 * 4;
  const size_t NEED = o;

  hipMemsetAsync(d_out, 0, (size_t)out_size * 4, stream);
  if (ws_size < NEED) {
    ws_too_small_k<<<1, 64, 0, stream>>>(out, (float)ws_size);
    return;
  }

  __bf16* xb   = (__bf16*)(ws + o_xb);
  __bf16* w1t  = (__bf16*)(ws + o_w1t);
  __bf16* w2t  = (__bf16*)(ws + o_w2t);
  __bf16* hbuf = (__bf16*)(ws + o_hbuf);
  int*   slot_tok  = (int*)(ws + o_slot_tok);
  float* slot_gate = (float*)(ws + o_slot_gate);
  int*   tok_e    = (int*)(ws + o_tok_e);
  int*   tok_pos  = (int*)(ws + o_tok_pos);
  float* tok_gate = (float*)(ws + o_tok_gate);
  int*   cnt  = (int*)(ws + o_cnt);
  int*   offs = (int*)(ws + o_offs);
  int*   tile_e = (int*)(ws + o_tile);
  int*   tile_m = tile_e + MAXTILES;

  hipMemsetAsync(cnt, 0, 64, stream);

  // weight transposes (bf16 pair-pack scheme)
  transpose_cvt2<<<dim3(FDIM / 32, HDIM / 128, NEXP), 256, 0, stream>>>(w1, w1t, HDIM, FDIM);
  transpose_cvt2<<<dim3(HDIM / 32, FDIM / 128, NEXP), 256, 0, stream>>>(w2, w2t, FDIM, HDIM);

  router_k<<<T_TOK / 4, 256, 0, stream>>>(x, rw, xb, cnt, tok_e, tok_pos, tok_gate);
  offs_k<<<1, 64, 0, stream>>>(cnt, offs, tile_e, tile_m);
  build_k<<<T_TOK * 2 / 256, 256, 0, stream>>>(tok_e, tok_pos, tok_gate, offs, slot_tok, slot_gate);

  // GEMM1: [cnt_e,1024] x [1024,4096] -> gelu -> hbuf
  moe_gemm<true><<<dim3(FDIM / 128, MAXTILES), 256, 0, stream>>>(
      xb, w1t, b1, hbuf, nullptr, cnt, offs, slot_tok, slot_gate, tile_e, tile_m, FDIM, HDIM);
  // GEMM2: [cnt_e,4096] x [4096,1024] -> gate*( +b2) -> atomic out
  moe_gemm<false><<<dim3(HDIM / 128, MAXTILES), 256, 0, stream>>>(
      hbuf, w2t, b2, nullptr, out, cnt, offs, slot_tok, slot_gate, tile_e, tile_m, HDIM, FDIM);
}

// Round 3
// 674.519 us; speedup vs baseline: 1.2215x; 1.0243x over previous
//
#include <hip/hip_runtime.h>
#include <math.h>

// Problem constants (B=2, S=2048 -> T=4096 tokens)
#define T_TOK 4096
#define HDIM  1024
#define FDIM  4096
#define NEXP  8
#define SLOT_CAP 9216   // 8192 pairs + 8 experts * 128 alignment pad
#define MAXTILES 72

typedef __bf16 bf16x8 __attribute__((ext_vector_type(8)));
typedef float  f32x4  __attribute__((ext_vector_type(4)));

__device__ __forceinline__ void gload_lds16(const void* g, void* l) {
  __builtin_amdgcn_global_load_lds((const __attribute__((address_space(1))) void*)g,
                                   (__attribute__((address_space(3))) void*)l,
                                   16, 0, 0);
}

// Fast GELU (tanh form): x * sig where sig = e/(e+1), e = exp(2*0.79788456*(x+0.044715x^3)).
// Written as x - x*rcp(e+1) so e=inf -> x, e=0 -> 0. Max |delta| vs exact-erf ~1e-3.
__device__ __forceinline__ float gelu_fast(float x) {
  float x2 = x * x;
  float p = fmaf(x2, 0.0356774081f, 0.7978845608f);     // 0.79788456*(1+0.044715 x^2)
  float z = x * p * 2.8853900818f;                       // *2*log2(e)
  float e = __builtin_amdgcn_exp2f(z);
  float r = __builtin_amdgcn_rcpf(e + 1.0f);
  return fmaf(-x, r, x);
}

// ---------------- router: scores, top-2, bf16 cast of x ----------------
__global__ void router_k(const float* __restrict__ x, const float* __restrict__ rw,
                         __bf16* __restrict__ xb, int* __restrict__ cnt,
                         int* __restrict__ tok_e, int* __restrict__ tok_pos,
                         float* __restrict__ tok_gate) {
  const int wv   = threadIdx.x >> 6;
  const int lane = threadIdx.x & 63;
  const int t = blockIdx.x * 4 + wv;
  const float* xr = x + (size_t)t * HDIM;
  __bf16* xbr = xb + (size_t)t * HDIM;
  float acc[8];
#pragma unroll
  for (int e = 0; e < 8; ++e) acc[e] = 0.0f;
#pragma unroll
  for (int i = 0; i < 16; ++i) {
    int h = lane + (i << 6);
    float xv = xr[h];
    xbr[h] = (__bf16)xv;
    const float4* rp = (const float4*)(rw + h * 8);
    float4 r0 = rp[0], r1 = rp[1];
    acc[0] += xv * r0.x; acc[1] += xv * r0.y; acc[2] += xv * r0.z; acc[3] += xv * r0.w;
    acc[4] += xv * r1.x; acc[5] += xv * r1.y; acc[6] += xv * r1.z; acc[7] += xv * r1.w;
  }
#pragma unroll
  for (int s = 32; s >= 1; s >>= 1) {
#pragma unroll
    for (int e = 0; e < 8; ++e) acc[e] += __shfl_xor(acc[e], s, 64);
  }
  if (lane == 0) {
    float v0 = acc[0]; int b0 = 0;
#pragma unroll
    for (int e = 1; e < 8; ++e) { if (acc[e] > v0) { v0 = acc[e]; b0 = e; } }
    float v1 = -1e30f; int b1i = 0;
#pragma unroll
    for (int e = 0; e < 8; ++e) { if (e != b0 && acc[e] > v1) { v1 = acc[e]; b1i = e; } }
    float g0 = 1.0f / (1.0f + expf(-v0));
    float g1 = 1.0f / (1.0f + expf(-v1));
    int p0 = atomicAdd(&cnt[b0], 1);
    int p1 = atomicAdd(&cnt[b1i], 1);
    tok_e[t * 2] = b0;    tok_e[t * 2 + 1] = b1i;
    tok_pos[t * 2] = p0;  tok_pos[t * 2 + 1] = p1;
    tok_gate[t * 2] = g0; tok_gate[t * 2 + 1] = g1;
  }
}

// ------- prefix offsets (128-aligned per expert) + flattened tile list -------
__global__ void offs_k(const int* __restrict__ cnt, int* __restrict__ offs,
                       int* __restrict__ tile_e, int* __restrict__ tile_m) {
  if (threadIdx.x == 0) {
    int r = 0, t = 0;
    for (int e = 0; e < NEXP; ++e) {
      offs[e] = r;
      int nt = (cnt[e] + 127) >> 7;
      for (int m = 0; m < nt; ++m) { tile_e[t] = e; tile_m[t] = m; ++t; }
      r += nt << 7;
    }
    for (; t < MAXTILES; ++t) { tile_e[t] = 0; tile_m[t] = 1 << 20; }
  }
}

// ---------------- scatter pairs into slot order ----------------
__global__ void build_k(const int* __restrict__ tok_e, const int* __restrict__ tok_pos,
                        const float* __restrict__ tok_gate, const int* __restrict__ offs,
                        int* __restrict__ slot_tok, float* __restrict__ slot_gate) {
  int idx = blockIdx.x * blockDim.x + threadIdx.x;   // 0..8191
  int e = tok_e[idx];
  int slot = offs[e] + tok_pos[idx];
  slot_tok[slot] = idx >> 1;
  slot_gate[slot] = tok_gate[idx];
}

// ------------- fp32 -> bf16 transposed weight copy (pair-pack) -------------
__global__ __launch_bounds__(256) void transpose_cvt2(const float* __restrict__ in,
                                                      __bf16* __restrict__ outp,
                                                      int R, int C) {
  __shared__ unsigned int pt[32][68];
  const int e = blockIdx.z;
  const int c0 = blockIdx.x * 32;
  const int r0 = blockIdx.y * 128;
  const int tid = threadIdx.x;
  const float* ibase = in + (size_t)e * R * C + (size_t)r0 * C + c0;
  const int rp = tid >> 3;
  const int cq = (tid & 7) * 4;
#pragma unroll
  for (int i = 0; i < 2; ++i) {
    int p = rp + 32 * i;
    const float4 v0 = *(const float4*)(ibase + (size_t)(2 * p) * C + cq);
    const float4 v1 = *(const float4*)(ibase + (size_t)(2 * p + 1) * C + cq);
    union { __bf16 h[2]; unsigned int u; } pk;
    pk.h[0] = (__bf16)v0.x; pk.h[1] = (__bf16)v1.x; pt[cq + 0][p] = pk.u;
    pk.h[0] = (__bf16)v0.y; pk.h[1] = (__bf16)v1.y; pt[cq + 1][p] = pk.u;
    pk.h[0] = (__bf16)v0.z; pk.h[1] = (__bf16)v1.z; pt[cq + 2][p] = pk.u;
    pk.h[0] = (__bf16)v0.w; pk.h[1] = (__bf16)v1.w; pt[cq + 3][p] = pk.u;
  }
  __syncthreads();
  const int rs = tid & 7;
  const int cc = tid >> 3;
  __bf16* obase = outp + (size_t)e * R * C + (size_t)c0 * R + r0;
#pragma unroll
  for (int i = 0; i < 2; ++i) {
    int ch = rs + 8 * i;
    uint4 v = *(const uint4*)&pt[cc][ch * 4];
    *(uint4*)(obase + (size_t)cc * R + ch * 8) = v;
  }
}

// ---------------- grouped GEMM, 128x128xBK64, XOR-swizzled LDS ----------------
// G1: A = xb gathered by slot_tok, epilogue = gelu_fast(acc+b1) -> hout (bf16)
// !G1: A = hout rows (slot-major), epilogue = (acc+b2) -> ybuf (bf16, per-slot)
template<bool G1>
__global__ __launch_bounds__(256) void moe_gemm(
    const __bf16* __restrict__ A, const __bf16* __restrict__ B,
    const float* __restrict__ bias,
    __bf16* __restrict__ hout,
    const int* __restrict__ cnt, const int* __restrict__ offs,
    const int* __restrict__ slot_tok,
    const int* __restrict__ tile_e, const int* __restrict__ tile_m,
    int N, int K)
{
  const int e = tile_e[blockIdx.y];
  const int mtile = tile_m[blockIdx.y];
  const int cnt_e = cnt[e];
  if (mtile * 128 >= cnt_e) return;
  const int offs_e = offs[e];
  const int nbase = blockIdx.x * 128;

  __shared__ __bf16 As[128 * 64];
  __shared__ __bf16 Bs[128 * 64];

  const int tid = threadIdx.x;
  const int w = tid >> 6, lane = tid & 63;
  const int wy = w >> 1, wx = w & 1;
  const int lm = lane & 15, quad = lane >> 4;
  const int lm7 = lane & 7;
  const int srow = lane >> 3;     // 0..7
  const int scol = lane & 7;      // 0..7, x8 elements

  const __bf16* aptr[4];
  const __bf16* bptr[4];
#pragma unroll
  for (int it = 0; it < 4; ++it) {
    int rl = w * 32 + it * 8 + srow;        // tile row 0..127
    long arow;
    if constexpr (G1) {
      int gm = mtile * 128 + rl;
      int tok = (gm < cnt_e) ? slot_tok[offs_e + gm] : 0;
      arow = (long)tok;
    } else {
      arow = (long)(offs_e + mtile * 128 + rl);
    }
    const int swcol = (scol ^ srow) << 3;   // swizzled source column
    aptr[it] = A + arow * (long)K + swcol;
    bptr[it] = B + ((long)e * N + nbase + rl) * (long)K + swcol;
  }

  f32x4 acc[4][4];
#pragma unroll
  for (int mt = 0; mt < 4; ++mt)
#pragma unroll
    for (int nt = 0; nt < 4; ++nt) acc[mt][nt] = (f32x4){0.f, 0.f, 0.f, 0.f};

  const int ksteps = K >> 6;
  for (int ks = 0; ks < ksteps; ++ks) {
    const int kofs = ks * 64;
#pragma unroll
    for (int it = 0; it < 4; ++it)
      gload_lds16(aptr[it] + kofs, &As[(w * 32 + it * 8) * 64]);
#pragma unroll
    for (int it = 0; it < 4; ++it)
      gload_lds16(bptr[it] + kofs, &Bs[(w * 32 + it * 8) * 64]);
    __syncthreads();

    const bf16x8* Af = reinterpret_cast<const bf16x8*>(As);
    const bf16x8* Bf = reinterpret_cast<const bf16x8*>(Bs);
#pragma unroll
    for (int kf = 0; kf < 2; ++kf) {
      bf16x8 a[4], b[4];
#pragma unroll
      for (int mt = 0; mt < 4; ++mt)
        a[mt] = Af[(wy * 64 + mt * 16 + lm) * 8 + (((kf << 2) + quad) ^ lm7)];
#pragma unroll
      for (int nt = 0; nt < 4; ++nt)
        b[nt] = Bf[(wx * 64 + nt * 16 + lm) * 8 + (((kf << 2) + quad) ^ lm7)];
#pragma unroll
      for (int mt = 0; mt < 4; ++mt)
#pragma unroll
        for (int nt = 0; nt < 4; ++nt)
          acc[mt][nt] = __builtin_amdgcn_mfma_f32_16x16x32_bf16(a[mt], b[nt], acc[mt][nt], 0, 0, 0);
    }
    __syncthreads();
  }

  // Epilogue: bf16 store to hout[slot_row * N + n]; G1 applies gelu_fast.
#pragma unroll
  for (int nt = 0; nt < 4; ++nt) {
    int n = nbase + wx * 64 + nt * 16 + lm;
    float bv = bias[e * N + n];
#pragma unroll
    for (int mt = 0; mt < 4; ++mt) {
      int mrow = wy * 64 + mt * 16 + quad * 4;
      f32x4 c = acc[mt][nt];
#pragma unroll
      for (int i = 0; i < 4; ++i) {
        int gm = mtile * 128 + mrow + i;
        if (gm < cnt_e) {
          float v = c[i] + bv;
          if constexpr (G1) v = gelu_fast(v);
          hout[(size_t)(offs_e + gm) * (size_t)N + n] = (__bf16)v;
        }
      }
    }
  }
}

// ---------------- combine: out[t] = g0*y[s0] + g1*y[s1] ----------------
typedef __bf16 bf16x4v __attribute__((ext_vector_type(4)));
__global__ __launch_bounds__(256) void combine_k(const __bf16* __restrict__ y,
                                                 const int* __restrict__ tok_e,
                                                 const int* __restrict__ tok_pos,
                                                 const float* __restrict__ tok_gate,
                                                 const int* __restrict__ offs,
                                                 float* __restrict__ out) {
  const int t = blockIdx.x;
  const int e0 = tok_e[t * 2], e1 = tok_e[t * 2 + 1];
  const long s0 = offs[e0] + tok_pos[t * 2];
  const long s1 = offs[e1] + tok_pos[t * 2 + 1];
  const float g0 = tok_gate[t * 2], g1 = tok_gate[t * 2 + 1];
  const int h0 = threadIdx.x * 4;
  bf16x4v a = *(const bf16x4v*)(y + s0 * HDIM + h0);
  bf16x4v b = *(const bf16x4v*)(y + s1 * HDIM + h0);
  float4 o;
  o.x = g0 * (float)a[0] + g1 * (float)b[0];
  o.y = g0 * (float)a[1] + g1 * (float)b[1];
  o.z = g0 * (float)a[2] + g1 * (float)b[2];
  o.w = g0 * (float)a[3] + g1 * (float)b[3];
  *(float4*)(out + (size_t)t * HDIM + h0) = o;
}

__global__ void ws_too_small_k(float* out, float v) {
  if (threadIdx.x == 0 && blockIdx.x == 0) out[0] = v;
}

extern "C" void kernel_launch(void* const* d_in, const int* in_sizes, int n_in,
                              void* d_out, int out_size, void* d_ws, size_t ws_size,
                              hipStream_t stream) {
  const float* x  = (const float*)d_in[0];   // [2,2048,1024]
  const float* rw = (const float*)d_in[1];   // [1024,8]
  const float* w1 = (const float*)d_in[2];   // [8,1024,4096]
  const float* b1 = (const float*)d_in[3];   // [8,4096]
  const float* w2 = (const float*)d_in[4];   // [8,4096,1024]
  const float* b2 = (const float*)d_in[5];   // [8,1024]
  float* out = (float*)d_out;
  char* ws = (char*)d_ws;

  // workspace layout
  size_t o = 0;
  size_t o_xb = o;        o += (size_t)T_TOK * HDIM * 2;            // bf16 x
  size_t o_w1t = o;       o += (size_t)NEXP * FDIM * HDIM * 2;      // bf16 [E][F][H]
  size_t o_w2t = o;       o += (size_t)NEXP * HDIM * FDIM * 2;      // bf16 [E][H][F]
  size_t o_hbuf = o;      o += (size_t)SLOT_CAP * FDIM * 2;         // bf16 gelu acts
  size_t o_ybuf = o;      o += (size_t)SLOT_CAP * HDIM * 2;         // bf16 per-slot y
  size_t o_slot_tok = o;  o += (size_t)SLOT_CAP * 4;
  size_t o_slot_gate = o; o += (size_t)SLOT_CAP * 4;
  size_t o_tok_e = o;     o += (size_t)T_TOK * 2 * 4;
  size_t o_tok_pos = o;   o += (size_t)T_TOK * 2 * 4;
  size_t o_tok_gate = o;  o += (size_t)T_TOK * 2 * 4;
  size_t o_cnt = o;       o += 64;
  size_t o_offs = o;      o += 64;
  size_t o_tile = o;      o += MAXTILES * 2 * 4;
  const size_t NEED = o;

  if (ws_size < NEED) {
    ws_too_small_k<<<1, 64, 0, stream>>>(out, (float)ws_size);
    return;
  }

  __bf16* xb   = (__bf16*)(ws + o_xb);
  __bf16* w1t  = (__bf16*)(ws + o_w1t);
  __bf16* w2t  = (__bf16*)(ws + o_w2t);
  __bf16* hbuf = (__bf16*)(ws + o_hbuf);
  __bf16* ybuf = (__bf16*)(ws + o_ybuf);
  int*   slot_tok  = (int*)(ws + o_slot_tok);
  float* slot_gate = (float*)(ws + o_slot_gate);
  int*   tok_e    = (int*)(ws + o_tok_e);
  int*   tok_pos  = (int*)(ws + o_tok_pos);
  float* tok_gate = (float*)(ws + o_tok_gate);
  int*   cnt  = (int*)(ws + o_cnt);
  int*   offs = (int*)(ws + o_offs);
  int*   tile_e = (int*)(ws + o_tile);
  int*   tile_m = tile_e + MAXTILES;

  hipMemsetAsync(cnt, 0, 64, stream);

  // weight transposes (bf16 pair-pack scheme)
  transpose_cvt2<<<dim3(FDIM / 32, HDIM / 128, NEXP), 256, 0, stream>>>(w1, w1t, HDIM, FDIM);
  transpose_cvt2<<<dim3(HDIM / 32, FDIM / 128, NEXP), 256, 0, stream>>>(w2, w2t, FDIM, HDIM);

  router_k<<<T_TOK / 4, 256, 0, stream>>>(x, rw, xb, cnt, tok_e, tok_pos, tok_gate);
  offs_k<<<1, 64, 0, stream>>>(cnt, offs, tile_e, tile_m);
  build_k<<<T_TOK * 2 / 256, 256, 0, stream>>>(tok_e, tok_pos, tok_gate, offs, slot_tok, slot_gate);

  // GEMM1: [cnt_e,1024] x [1024,4096] -> gelu -> hbuf
  moe_gemm<true><<<dim3(FDIM / 128, MAXTILES), 256, 0, stream>>>(
      xb, w1t, b1, hbuf, cnt, offs, slot_tok, tile_e, tile_m, FDIM, HDIM);
  // GEMM2: [cnt_e,4096] x [4096,1024] -> +b2 -> ybuf (per-slot, no atomics)
  moe_gemm<false><<<dim3(HDIM / 128, MAXTILES), 256, 0, stream>>>(
      hbuf, w2t, b2, ybuf, cnt, offs, slot_tok, tile_e, tile_m, HDIM, FDIM);
  // combine: out[t] = g0*y[s0] + g1*y[s1]  (writes every output element)
  combine_k<<<T_TOK, 256, 0, stream>>>(ybuf, tok_e, tok_pos, tok_gate, offs, out);
}